// Round 1
// baseline (5675.582 us; speedup 1.0000x reference)
//
#include <hip/hip_runtime.h>
#include <stdint.h>
#include <math.h>

// ---------------- problem constants ----------------
#define B_SZ 32
#define C_IN 64
#define T_SZ 512
#define NFILT 256
#define KW 9
#define H_SZ 512
#define N_CLS 50
#define NWG_SCAN 96   // 3 layers x 32 WGs

typedef __bf16 bf16x8 __attribute__((ext_vector_type(8)));
typedef float f32x16 __attribute__((ext_vector_type(16)));

#define MFMA32(a, b, c) __builtin_amdgcn_mfma_f32_32x32x16_bf16((a), (b), (c), 0, 0, 0)

// ---------------- grid barrier (96 co-resident WGs, agent scope) ----------------
__device__ __forceinline__ void grid_barrier(unsigned* bar) {
  __syncthreads();
  if (threadIdx.x == 0) {
    unsigned* cnt = bar;        // cache line 0
    unsigned* gen = bar + 64;   // cache line 1
    unsigned g0 = __hip_atomic_load(gen, __ATOMIC_RELAXED, __HIP_MEMORY_SCOPE_AGENT);
    unsigned a = __hip_atomic_fetch_add(cnt, 1u, __ATOMIC_ACQ_REL, __HIP_MEMORY_SCOPE_AGENT);
    if (a == NWG_SCAN - 1) {
      __hip_atomic_store(cnt, 0u, __ATOMIC_RELAXED, __HIP_MEMORY_SCOPE_AGENT);
      __hip_atomic_fetch_add(gen, 1u, __ATOMIC_RELEASE, __HIP_MEMORY_SCOPE_AGENT);
    } else {
      while (__hip_atomic_load(gen, __ATOMIC_RELAXED, __HIP_MEMORY_SCOPE_AGENT) == g0)
        __builtin_amdgcn_s_sleep(2);
      (void)__hip_atomic_load(gen, __ATOMIC_ACQUIRE, __HIP_MEMORY_SCOPE_AGENT);
    }
  }
  __syncthreads();
}

// ---------------- conv1d + groupnorm + relu, write bf16 hi/lo (B,T,F) ----------------
// grid: 256 blocks = (b, group); block 256 threads; dyn LDS = (64*520+16)*4 bytes
__global__ __launch_bounds__(256, 1) void conv_gn_kernel(
    const float* __restrict__ x, const float* __restrict__ w,
    const float* __restrict__ gamma, const float* __restrict__ beta,
    __bf16* __restrict__ x1h, __bf16* __restrict__ x1l) {
  extern __shared__ float xs[];  // [64][520] padded rows + 16 floats reduction
  const int b = blockIdx.x >> 3;
  const int g = blockIdx.x & 7;
  const int tid = threadIdx.x;
  const float* xb = x + (size_t)b * (C_IN * T_SZ);
  // load x slice (vector float4), pad halo with zeros
  for (int i = tid; i < C_IN * T_SZ / 4; i += 256) {
    int c = i >> 7;
    int t4 = (i & 127) << 2;
    float4 v = *(const float4*)(xb + c * T_SZ + t4);
    *(float4*)(&xs[c * 520 + 4 + t4]) = v;
  }
  for (int i = tid; i < C_IN * 8; i += 256) {
    int c = i >> 3, j = i & 7;
    xs[c * 520 + (j < 4 ? j : 512 + j)] = 0.f;
  }
  __syncthreads();
  const int fl = tid & 31;            // local filter in group
  const int f = g * 32 + fl;          // global filter
  const int t0 = (tid >> 5) << 6;     // 64-wide t chunk
  float acc[64];
#pragma unroll
  for (int t = 0; t < 64; ++t) acc[t] = 0.f;
  const float* wf = w + (size_t)f * (C_IN * KW);
  for (int c = 0; c < C_IN; ++c) {
    float wr[9];
#pragma unroll
    for (int k = 0; k < 9; ++k) wr[k] = wf[c * 9 + k];
    float xr[72];
    const float* xrow = &xs[c * 520 + t0];
#pragma unroll
    for (int j = 0; j < 72; ++j) xr[j] = xrow[j];
#pragma unroll
    for (int t = 0; t < 64; ++t) {
      float s = acc[t];
#pragma unroll
      for (int k = 0; k < 9; ++k) s = fmaf(xr[t + k], wr[k], s);
      acc[t] = s;
    }
  }
  // group stats over all 32 ch x 512 t of this block
  float s1 = 0.f, s2 = 0.f;
#pragma unroll
  for (int t = 0; t < 64; ++t) { s1 += acc[t]; s2 = fmaf(acc[t], acc[t], s2); }
#pragma unroll
  for (int off = 32; off > 0; off >>= 1) {
    s1 += __shfl_down(s1, off);
    s2 += __shfl_down(s2, off);
  }
  float* red = xs + 64 * 520;
  if ((tid & 63) == 0) { red[tid >> 6] = s1; red[4 + (tid >> 6)] = s2; }
  __syncthreads();
  if (tid == 0) {
    float a = red[0] + red[1] + red[2] + red[3];
    float q = red[4] + red[5] + red[6] + red[7];
    float mu = a * (1.f / 16384.f);
    float var = q * (1.f / 16384.f) - mu * mu;
    red[8] = mu;
    red[9] = 1.f / sqrtf(var + 1e-5f);
  }
  __syncthreads();
  const float mu = red[8], inv = red[9];
  const float ga = gamma[f], be = beta[f];
#pragma unroll
  for (int t = 0; t < 64; ++t) {
    float v = (acc[t] - mu) * inv * ga + be;
    v = fmaxf(v, 0.f);
    __bf16 hh = (__bf16)v;
    __bf16 hl = (__bf16)(v - (float)hh);
    size_t idx = ((size_t)b * T_SZ + (t0 + t)) * NFILT + f;
    x1h[idx] = hh;
    x1l[idx] = hl;
  }
}

// ---------------- persistent pipelined 3-layer LSTM scan ----------------
// grid: 96 WGs x 256 threads. WG = (layer = wg/32, wgl = wg%32 -> units [wgl*16, wgl*16+16))
// Reordered gate columns n_loc = gate*16 + u  (orig row = gate*512 + wgl*16 + u).
// Waves: 0,1 = recurrent k-chunks [0,256),[256,512); 2,3 = xproj k-chunks.
// Weights resident in VGPRs as hi/lo bf16 MFMA B-fragments (exact-ish fp32 via 3 passes).
// A fragments read directly from global (L2-resident h/x buffers).
__global__ __launch_bounds__(256, 1) void lstm_scan_kernel(
    const float* __restrict__ wih1, const float* __restrict__ whh1, const float* __restrict__ bb1,
    const float* __restrict__ wih2, const float* __restrict__ whh2, const float* __restrict__ bb2,
    const float* __restrict__ wih3, const float* __restrict__ whh3, const float* __restrict__ bb3,
    const __bf16* __restrict__ x1h, const __bf16* __restrict__ x1l,
    __bf16* __restrict__ xAh, __bf16* __restrict__ xAl,
    __bf16* __restrict__ xBh, __bf16* __restrict__ xBl,
    __bf16* __restrict__ hbase,   // [parity2][layer3][hi/lo2][32*512]
    float* __restrict__ feat, unsigned* __restrict__ bar) {
  __shared__ float gl[4][32][64];  // per-wave partial gate tiles

  const int wg = blockIdx.x;
  const int layer = wg >> 5;
  const int wgl = wg & 31;
  const int tid = threadIdx.x;
  const int lane = tid & 63;
  const int wave = tid >> 6;

  const float* wih = layer == 0 ? wih1 : (layer == 1 ? wih2 : wih3);
  const float* whh = layer == 0 ? whh1 : (layer == 1 ? whh2 : whh3);
  const float* bias = layer == 0 ? bb1 : (layer == 1 ? bb2 : bb3);
  const int Din = layer == 0 ? NFILT : H_SZ;
  const __bf16* xinh = layer == 0 ? x1h : (layer == 1 ? xAh : xBh);
  const __bf16* xinl = layer == 0 ? x1l : (layer == 1 ? xAl : xBl);
  __bf16* xoh = layer == 0 ? xAh : xBh;
  __bf16* xol = layer == 0 ? xAl : xBl;

  const bool is_x = (wave >= 2);
  const int kbase = (wave & 1) << 8;  // 0 or 256
  // layer0 wave3 covers x-k [256,512) which doesn't exist (Din=256): all-zero weights
  const bool dead = (layer == 0) && (wave == 3);

  // ---- resident weight fragments (hi/lo bf16 split) ----
  bf16x8 wfh[2][16], wfl[2][16];
  {
    const float* wsrc = is_x ? wih : whh;
    const int wk = is_x ? Din : H_SZ;
#pragma unroll
    for (int nt = 0; nt < 2; ++nt) {
      const int nloc = nt * 32 + (lane & 31);
      const int orow = (nloc >> 4) * 512 + wgl * 16 + (nloc & 15);
      const float* wrow = wsrc + (size_t)orow * wk;
#pragma unroll
      for (int kt = 0; kt < 16; ++kt) {
        const int k0 = kbase + kt * 16 + ((lane >> 5) << 3);
        bf16x8 hi, lo;
#pragma unroll
        for (int e = 0; e < 8; ++e) {
          float v = 0.f;
          if (!is_x || (k0 + e) < Din) v = wrow[k0 + e];
          __bf16 h = (__bf16)v;
          hi[e] = h;
          lo[e] = (__bf16)(v - (float)h);
        }
        wfh[nt][kt] = hi;
        wfl[nt][kt] = lo;
      }
    }
  }

  // ---- cell-update constants: thread handles cells (m=cm0, u=cu) and (m=cm0+16, u=cu) ----
  const int cu = tid & 15;
  const int cm0 = tid >> 4;  // 0..15
  const int unit = wgl * 16 + cu;
  float cb4[4];
#pragma unroll
  for (int gg = 0; gg < 4; ++gg) cb4[gg] = bias[gg * 512 + unit];
  float cst[2] = {0.f, 0.f};
  float hsum[2] = {0.f, 0.f};

  const int arow = lane & 31;          // A row = batch
  const int agrp = (lane >> 5) << 3;   // k sub-group 0/8

  for (int s = 0; s < T_SZ + 2; ++s) {
    const int t = s - layer;
    if (t >= 0 && t < T_SZ) {
      f32x16 acc[2][2] = {};  // [ntile][kt parity]
      const bool active = is_x ? (!dead) : (t > 0);  // h_{-1}=0 -> skip recurrent at t==0
      if (active) {
        const __bf16 *ahb, *alb;
        if (is_x) {
          ahb = xinh + ((size_t)arow * T_SZ + t) * Din;
          alb = xinl + ((size_t)arow * T_SZ + t) * Din;
        } else {
          const int rp = (t - 1) & 1;  // parity of h_{t-1}
          const __bf16* hb = hbase + ((size_t)(rp * 3 + layer) * 2) * 16384;
          ahb = hb + (size_t)arow * 512;
          alb = hb + 16384 + (size_t)arow * 512;
        }
#pragma unroll
        for (int kt = 0; kt < 16; ++kt) {
          const int k0 = kbase + kt * 16 + agrp;
          const bf16x8 ah = *(const bf16x8*)(ahb + k0);
          const bf16x8 al = *(const bf16x8*)(alb + k0);
          const int p = kt & 1;
#pragma unroll
          for (int nt = 0; nt < 2; ++nt) {
            f32x16 a = acc[nt][p];
            a = MFMA32(ah, wfh[nt][kt], a);
            a = MFMA32(al, wfh[nt][kt], a);
            a = MFMA32(ah, wfl[nt][kt], a);
            acc[nt][p] = a;
          }
        }
      }
      // publish partial gate tiles
#pragma unroll
      for (int nt = 0; nt < 2; ++nt) {
        const f32x16 v = acc[nt][0] + acc[nt][1];
        const int n = nt * 32 + (lane & 31);
#pragma unroll
        for (int r = 0; r < 16; ++r) {
          const int m = (r & 3) + ((r >> 2) << 3) + ((lane >> 5) << 2);
          gl[wave][m][n] = v[r];
        }
      }
      __syncthreads();
      // cell update (2 cells per thread)
      __bf16* hw = hbase + ((size_t)((t & 1) * 3 + layer) * 2) * 16384;
#pragma unroll
      for (int cc = 0; cc < 2; ++cc) {
        const int m = cm0 + cc * 16;
        float gv[4];
#pragma unroll
        for (int gg = 0; gg < 4; ++gg) {
          gv[gg] = gl[0][m][gg * 16 + cu] + gl[1][m][gg * 16 + cu] +
                   gl[2][m][gg * 16 + cu] + gl[3][m][gg * 16 + cu] + cb4[gg];
        }
        const float ig = 1.f / (1.f + expf(-gv[0]));
        const float fg = 1.f / (1.f + expf(-gv[1]));
        const float gc = tanhf(gv[2]);
        const float og = 1.f / (1.f + expf(-gv[3]));
        const float c_ = fg * cst[cc] + ig * gc;
        cst[cc] = c_;
        const float h_ = og * tanhf(c_);
        const __bf16 hh = (__bf16)h_;
        const __bf16 hl = (__bf16)(h_ - (float)hh);
        hw[(size_t)m * 512 + unit] = hh;
        hw[16384 + (size_t)m * 512 + unit] = hl;
        if (layer < 2) {
          const size_t xo = ((size_t)m * T_SZ + t) * 512 + unit;
          xoh[xo] = hh;
          xol[xo] = hl;
        } else {
          hsum[cc] += h_;
        }
      }
    }
    grid_barrier(bar);
  }
  if (layer == 2) {
#pragma unroll
    for (int cc = 0; cc < 2; ++cc) {
      feat[(size_t)(cm0 + cc * 16) * 512 + unit] = hsum[cc] * (1.f / 512.f);
    }
  }
}

// ---------------- head: out[b][n] = feat[b]·head_w[n] + head_b[n] ----------------
__global__ void head_kernel(const float* __restrict__ feat, const float* __restrict__ hw,
                            const float* __restrict__ hb, float* __restrict__ out) {
  const int bi = blockIdx.x;
  const int b = bi / N_CLS;
  const int n = bi % N_CLS;
  const int lane = threadIdx.x;
  float s = 0.f;
  for (int j = lane; j < H_SZ; j += 64) s = fmaf(feat[b * H_SZ + j], hw[n * H_SZ + j], s);
#pragma unroll
  for (int off = 32; off > 0; off >>= 1) s += __shfl_down(s, off);
  if (lane == 0) out[b * N_CLS + n] = s + hb[n];
}

// ---------------- launch ----------------
extern "C" void kernel_launch(void* const* d_in, const int* in_sizes, int n_in,
                              void* d_out, int out_size, void* d_ws, size_t ws_size,
                              hipStream_t stream) {
  const float* x_emg = (const float*)d_in[0];
  const float* conv_w = (const float*)d_in[1];
  const float* gn_g = (const float*)d_in[2];
  const float* gn_b = (const float*)d_in[3];
  const float* head_w = (const float*)d_in[4];
  const float* head_b = (const float*)d_in[5];
  const float* wih1 = (const float*)d_in[6];
  const float* whh1 = (const float*)d_in[7];
  const float* b1 = (const float*)d_in[8];
  const float* wih2 = (const float*)d_in[9];
  const float* whh2 = (const float*)d_in[10];
  const float* b2 = (const float*)d_in[11];
  const float* wih3 = (const float*)d_in[12];
  const float* whh3 = (const float*)d_in[13];
  const float* b3 = (const float*)d_in[14];
  float* out = (float*)d_out;

  char* p = (char*)d_ws;
  auto alloc = [&](size_t sz) {
    char* r = p;
    p += (sz + 255) & ~(size_t)255;
    return r;
  };
  unsigned* bar = (unsigned*)alloc(512);
  __bf16* x1h = (__bf16*)alloc((size_t)B_SZ * T_SZ * NFILT * 2);
  __bf16* x1l = (__bf16*)alloc((size_t)B_SZ * T_SZ * NFILT * 2);
  __bf16* xAh = (__bf16*)alloc((size_t)B_SZ * T_SZ * H_SZ * 2);
  __bf16* xAl = (__bf16*)alloc((size_t)B_SZ * T_SZ * H_SZ * 2);
  __bf16* xBh = (__bf16*)alloc((size_t)B_SZ * T_SZ * H_SZ * 2);
  __bf16* xBl = (__bf16*)alloc((size_t)B_SZ * T_SZ * H_SZ * 2);
  __bf16* hbase = (__bf16*)alloc((size_t)2 * 3 * 2 * 16384 * 2);
  float* feat = (float*)alloc((size_t)B_SZ * H_SZ * 4);

  hipMemsetAsync(bar, 0, 512, stream);
  conv_gn_kernel<<<dim3(256), dim3(256), (64 * 520 + 16) * 4, stream>>>(
      x_emg, conv_w, gn_g, gn_b, x1h, x1l);
  lstm_scan_kernel<<<dim3(NWG_SCAN), dim3(256), 0, stream>>>(
      wih1, whh1, b1, wih2, whh2, b2, wih3, whh3, b3,
      x1h, x1l, xAh, xAl, xBh, xBl, hbase, feat, bar);
  head_kernel<<<dim3(B_SZ * N_CLS), dim3(64), 0, stream>>>(feat, head_w, head_b, out);
}

// Round 2
// 4888.394 us; speedup vs baseline: 1.1610x; 1.1610x over previous
//
#include <hip/hip_runtime.h>
#include <stdint.h>
#include <math.h>

// ---------------- problem constants ----------------
#define B_SZ 32
#define C_IN 64
#define T_SZ 512
#define NFILT 256
#define KW 9
#define H_SZ 512
#define N_CLS 50

typedef __bf16 bf16x8 __attribute__((ext_vector_type(8)));
typedef float f32x16 __attribute__((ext_vector_type(16)));

#define MFMA32(a, b, c) __builtin_amdgcn_mfma_f32_32x32x16_bf16((a), (b), (c), 0, 0, 0)

// system-scope (LLC-coherent, cache-bypassing) data movement for cross-XCD h exchange
__device__ __forceinline__ bf16x8 ld_frag_sys(const __bf16* p) {
  union { unsigned long long u[2]; bf16x8 v; } r;
  r.u[0] = __hip_atomic_load((const unsigned long long*)p, __ATOMIC_RELAXED,
                             __HIP_MEMORY_SCOPE_SYSTEM);
  r.u[1] = __hip_atomic_load((const unsigned long long*)(p + 4), __ATOMIC_RELAXED,
                             __HIP_MEMORY_SCOPE_SYSTEM);
  return r.v;
}
__device__ __forceinline__ void st_u32_sys(unsigned* p, unsigned v) {
  __hip_atomic_store(p, v, __ATOMIC_RELAXED, __HIP_MEMORY_SCOPE_SYSTEM);
}
__device__ __forceinline__ unsigned* flagp(unsigned* flags, int layer, int t) {
  return flags + (((size_t)layer * T_SZ + t) << 4);  // 64B stride per flag
}
__device__ __forceinline__ void wait_flag(const unsigned* f) {
  while (__hip_atomic_load(f, __ATOMIC_RELAXED, __HIP_MEMORY_SCOPE_SYSTEM) < 32u)
    __builtin_amdgcn_s_sleep(1);
}

// ---------------- conv1d + groupnorm + relu, write bf16 hi/lo (B,T,F) ----------------
__global__ __launch_bounds__(256, 1) void conv_gn_kernel(
    const float* __restrict__ x, const float* __restrict__ w,
    const float* __restrict__ gamma, const float* __restrict__ beta,
    __bf16* __restrict__ x1h, __bf16* __restrict__ x1l) {
  extern __shared__ float xs[];  // [64][520] padded rows + 16 floats reduction
  const int b = blockIdx.x >> 3;
  const int g = blockIdx.x & 7;
  const int tid = threadIdx.x;
  const float* xb = x + (size_t)b * (C_IN * T_SZ);
  for (int i = tid; i < C_IN * T_SZ / 4; i += 256) {
    int c = i >> 7;
    int t4 = (i & 127) << 2;
    float4 v = *(const float4*)(xb + c * T_SZ + t4);
    *(float4*)(&xs[c * 520 + 4 + t4]) = v;
  }
  for (int i = tid; i < C_IN * 8; i += 256) {
    int c = i >> 3, j = i & 7;
    xs[c * 520 + (j < 4 ? j : 512 + j)] = 0.f;
  }
  __syncthreads();
  const int fl = tid & 31;
  const int f = g * 32 + fl;
  const int t0 = (tid >> 5) << 6;
  float acc[64];
#pragma unroll
  for (int t = 0; t < 64; ++t) acc[t] = 0.f;
  const float* wf = w + (size_t)f * (C_IN * KW);
  for (int c = 0; c < C_IN; ++c) {
    float wr[9];
#pragma unroll
    for (int k = 0; k < 9; ++k) wr[k] = wf[c * 9 + k];
    float xr[72];
    const float* xrow = &xs[c * 520 + t0];
#pragma unroll
    for (int j = 0; j < 72; ++j) xr[j] = xrow[j];
#pragma unroll
    for (int t = 0; t < 64; ++t) {
      float s = acc[t];
#pragma unroll
      for (int k = 0; k < 9; ++k) s = fmaf(xr[t + k], wr[k], s);
      acc[t] = s;
    }
  }
  float s1 = 0.f, s2 = 0.f;
#pragma unroll
  for (int t = 0; t < 64; ++t) { s1 += acc[t]; s2 = fmaf(acc[t], acc[t], s2); }
#pragma unroll
  for (int off = 32; off > 0; off >>= 1) {
    s1 += __shfl_down(s1, off);
    s2 += __shfl_down(s2, off);
  }
  float* red = xs + 64 * 520;
  if ((tid & 63) == 0) { red[tid >> 6] = s1; red[4 + (tid >> 6)] = s2; }
  __syncthreads();
  if (tid == 0) {
    float a = red[0] + red[1] + red[2] + red[3];
    float q = red[4] + red[5] + red[6] + red[7];
    float mu = a * (1.f / 16384.f);
    float var = q * (1.f / 16384.f) - mu * mu;
    red[8] = mu;
    red[9] = 1.f / sqrtf(var + 1e-5f);
  }
  __syncthreads();
  const float mu = red[8], inv = red[9];
  const float ga = gamma[f], be = beta[f];
#pragma unroll
  for (int t = 0; t < 64; ++t) {
    float v = (acc[t] - mu) * inv * ga + be;
    v = fmaxf(v, 0.f);
    __bf16 hh = (__bf16)v;
    __bf16 hl = (__bf16)(v - (float)hh);
    size_t idx = ((size_t)b * T_SZ + (t0 + t)) * NFILT + f;
    x1h[idx] = hh;
    x1l[idx] = hl;
  }
}

// ---------------- self-timed pipelined 3-layer LSTM scan (flag-sync, no global barrier) --
// 96 WGs x 256 threads. WG = (layer = wg/32, wgl = wg%32 -> units [wgl*16, wgl*16+16)).
// Waves 0,1 = recurrent k-halves (poll done[layer][t-1]); waves 2,3 = xproj (poll
// done[layer-1][t]). h exchange via system-scope LLC ops; x streams plain/cached reads,
// LLC-visible writes. Weights resident in VGPRs, fp32-ish via bf16 hi/lo 3-pass MFMA.
__global__ __launch_bounds__(256, 1) void lstm_scan_kernel(
    const float* __restrict__ wih1, const float* __restrict__ whh1, const float* __restrict__ bb1,
    const float* __restrict__ wih2, const float* __restrict__ whh2, const float* __restrict__ bb2,
    const float* __restrict__ wih3, const float* __restrict__ whh3, const float* __restrict__ bb3,
    const __bf16* __restrict__ x1h, const __bf16* __restrict__ x1l,
    __bf16* __restrict__ xAh, __bf16* __restrict__ xAl,
    __bf16* __restrict__ xBh, __bf16* __restrict__ xBl,
    __bf16* __restrict__ hbase,  // [parity2][layer3][hi/lo2][32*512]
    float* __restrict__ feat, unsigned* __restrict__ flags) {
  __shared__ float gl[4][32][72];  // per-wave partial gate tiles, stride 72 (bank-friendly)

  const int wg = blockIdx.x;
  const int layer = wg >> 5;
  const int wgl = wg & 31;
  const int tid = threadIdx.x;
  const int lane = tid & 63;
  const int wave = tid >> 6;

  const float* wih = layer == 0 ? wih1 : (layer == 1 ? wih2 : wih3);
  const float* whh = layer == 0 ? whh1 : (layer == 1 ? whh2 : whh3);
  const float* bias = layer == 0 ? bb1 : (layer == 1 ? bb2 : bb3);
  const int Din = layer == 0 ? NFILT : H_SZ;
  const __bf16* xinh = layer == 0 ? x1h : (layer == 1 ? xAh : xBh);
  const __bf16* xinl = layer == 0 ? x1l : (layer == 1 ? xAl : xBl);
  __bf16* xoh = layer == 0 ? xAh : xBh;
  __bf16* xol = layer == 0 ? xAl : xBl;

  const bool is_x = (wave >= 2);
  const int kbase = (wave & 1) << 8;
  const bool dead = (layer == 0) && (wave == 3);  // layer0 x-k [256,512) doesn't exist

  // ---- resident weight fragments (hi/lo bf16 split) ----
  bf16x8 wfh[2][16], wfl[2][16];
  {
    const float* wsrc = is_x ? wih : whh;
    const int wk = is_x ? Din : H_SZ;
#pragma unroll
    for (int nt = 0; nt < 2; ++nt) {
      const int nloc = nt * 32 + (lane & 31);
      const int orow = (nloc >> 4) * 512 + wgl * 16 + (nloc & 15);
      const float* wrow = wsrc + (size_t)orow * wk;
#pragma unroll
      for (int kt = 0; kt < 16; ++kt) {
        const int k0 = kbase + kt * 16 + ((lane >> 5) << 3);
        bf16x8 hi, lo;
#pragma unroll
        for (int e = 0; e < 8; ++e) {
          float v = 0.f;
          if (!is_x || (k0 + e) < Din) v = wrow[k0 + e];
          __bf16 h = (__bf16)v;
          hi[e] = h;
          lo[e] = (__bf16)(v - (float)h);
        }
        wfh[nt][kt] = hi;
        wfl[nt][kt] = lo;
      }
    }
  }

  // ---- cell-update mapping: thread -> batch row cm, unit pair (2 consecutive units) ----
  const int cm = tid >> 3;       // 0..31 batch row
  const int cq = tid & 7;        // unit pair index
  const int ul0 = cq * 2;        // local unit 0..14 (even)
  const int unit0 = wgl * 16 + ul0;
  float cb[4][2];
#pragma unroll
  for (int gg = 0; gg < 4; ++gg) {
    cb[gg][0] = bias[gg * 512 + unit0];
    cb[gg][1] = bias[gg * 512 + unit0 + 1];
  }
  float cst[2] = {0.f, 0.f};
  float hsum[2] = {0.f, 0.f};

  const int arow = lane & 31;         // A row = batch
  const int agrp = (lane >> 5) << 3;  // k sub-group 0/8

  for (int t = 0; t < T_SZ; ++t) {
    f32x16 acc[2][2] = {};  // [ntile][kt parity]
    if (!is_x) {
      if (t > 0) {  // h_{-1} = 0 -> skip recurrent MFMAs at t==0
        wait_flag(flagp(flags, layer, t - 1));
        const int rp = (t - 1) & 1;
        const __bf16* hb = hbase + ((size_t)(rp * 3 + layer) * 2) * 16384;
        const __bf16* ahb = hb + (size_t)arow * 512;
        const __bf16* alb = hb + 16384 + (size_t)arow * 512;
#pragma unroll
        for (int kt = 0; kt < 16; ++kt) {
          const int k0 = kbase + kt * 16 + agrp;
          const bf16x8 ah = ld_frag_sys(ahb + k0);
          const bf16x8 al = ld_frag_sys(alb + k0);
          const int p = kt & 1;
#pragma unroll
          for (int nt = 0; nt < 2; ++nt) {
            f32x16 a = acc[nt][p];
            a = MFMA32(ah, wfh[nt][kt], a);
            a = MFMA32(al, wfh[nt][kt], a);
            a = MFMA32(ah, wfl[nt][kt], a);
            acc[nt][p] = a;
          }
        }
      }
    } else if (!dead) {
      if (layer > 0) wait_flag(flagp(flags, layer - 1, t));
      const __bf16* ahb = xinh + ((size_t)arow * T_SZ + t) * Din;
      const __bf16* alb = xinl + ((size_t)arow * T_SZ + t) * Din;
#pragma unroll
      for (int kt = 0; kt < 16; ++kt) {
        const int k0 = kbase + kt * 16 + agrp;
        const bf16x8 ah = *(const bf16x8*)(ahb + k0);
        const bf16x8 al = *(const bf16x8*)(alb + k0);
        const int p = kt & 1;
#pragma unroll
        for (int nt = 0; nt < 2; ++nt) {
          f32x16 a = acc[nt][p];
          a = MFMA32(ah, wfh[nt][kt], a);
          a = MFMA32(al, wfh[nt][kt], a);
          a = MFMA32(ah, wfl[nt][kt], a);
          acc[nt][p] = a;
        }
      }
    }
    // publish partial gate tiles
#pragma unroll
    for (int nt = 0; nt < 2; ++nt) {
      const f32x16 v = acc[nt][0] + acc[nt][1];
      const int n = nt * 32 + (lane & 31);
#pragma unroll
      for (int r = 0; r < 16; ++r) {
        const int m = (r & 3) + ((r >> 2) << 3) + ((lane >> 5) << 2);
        gl[wave][m][n] = v[r];
      }
    }
    __syncthreads();
    // cell update: 2 consecutive units at batch row cm
    {
      __bf16* hw = hbase + ((size_t)((t & 1) * 3 + layer) * 2) * 16384;
      float hv[2];
#pragma unroll
      for (int j = 0; j < 2; ++j) {
        float gv[4];
#pragma unroll
        for (int gg = 0; gg < 4; ++gg) {
          gv[gg] = gl[0][cm][gg * 16 + ul0 + j] + gl[1][cm][gg * 16 + ul0 + j] +
                   gl[2][cm][gg * 16 + ul0 + j] + gl[3][cm][gg * 16 + ul0 + j] + cb[gg][j];
        }
        const float ig = 1.f / (1.f + expf(-gv[0]));
        const float fg = 1.f / (1.f + expf(-gv[1]));
        const float gc = tanhf(gv[2]);
        const float og = 1.f / (1.f + expf(-gv[3]));
        const float c_ = fg * cst[j] + ig * gc;
        cst[j] = c_;
        hv[j] = og * tanhf(c_);
      }
      union { __bf16 b[2]; unsigned u; } ph, pl;
      ph.b[0] = (__bf16)hv[0];
      ph.b[1] = (__bf16)hv[1];
      pl.b[0] = (__bf16)(hv[0] - (float)ph.b[0]);
      pl.b[1] = (__bf16)(hv[1] - (float)ph.b[1]);
      st_u32_sys((unsigned*)(hw + (size_t)cm * 512 + unit0), ph.u);
      st_u32_sys((unsigned*)(hw + 16384 + (size_t)cm * 512 + unit0), pl.u);
      if (layer < 2) {
        const size_t xo = ((size_t)cm * T_SZ + t) * 512 + unit0;
        st_u32_sys((unsigned*)(xoh + xo), ph.u);
        st_u32_sys((unsigned*)(xol + xo), pl.u);
      } else {
        hsum[0] += hv[0];
        hsum[1] += hv[1];
      }
    }
    __syncthreads();  // drains each thread's vmem (stores ack'd at LLC) + protects gl
    if (tid == 0)
      __hip_atomic_fetch_add(flagp(flags, layer, t), 1u, __ATOMIC_RELAXED,
                             __HIP_MEMORY_SCOPE_SYSTEM);
  }
  if (layer == 2) {
    feat[(size_t)cm * 512 + unit0] = hsum[0] * (1.f / 512.f);
    feat[(size_t)cm * 512 + unit0 + 1] = hsum[1] * (1.f / 512.f);
  }
}

// ---------------- head ----------------
__global__ void head_kernel(const float* __restrict__ feat, const float* __restrict__ hw,
                            const float* __restrict__ hb, float* __restrict__ out) {
  const int bi = blockIdx.x;
  const int b = bi / N_CLS;
  const int n = bi % N_CLS;
  const int lane = threadIdx.x;
  float s = 0.f;
  for (int j = lane; j < H_SZ; j += 64) s = fmaf(feat[b * H_SZ + j], hw[n * H_SZ + j], s);
#pragma unroll
  for (int off = 32; off > 0; off >>= 1) s += __shfl_down(s, off);
  if (lane == 0) out[b * N_CLS + n] = s + hb[n];
}

// ---------------- launch ----------------
extern "C" void kernel_launch(void* const* d_in, const int* in_sizes, int n_in,
                              void* d_out, int out_size, void* d_ws, size_t ws_size,
                              hipStream_t stream) {
  const float* x_emg = (const float*)d_in[0];
  const float* conv_w = (const float*)d_in[1];
  const float* gn_g = (const float*)d_in[2];
  const float* gn_b = (const float*)d_in[3];
  const float* head_w = (const float*)d_in[4];
  const float* head_b = (const float*)d_in[5];
  const float* wih1 = (const float*)d_in[6];
  const float* whh1 = (const float*)d_in[7];
  const float* b1 = (const float*)d_in[8];
  const float* wih2 = (const float*)d_in[9];
  const float* whh2 = (const float*)d_in[10];
  const float* b2 = (const float*)d_in[11];
  const float* wih3 = (const float*)d_in[12];
  const float* whh3 = (const float*)d_in[13];
  const float* b3 = (const float*)d_in[14];
  float* out = (float*)d_out;

  char* p = (char*)d_ws;
  auto alloc = [&](size_t sz) {
    char* r = p;
    p += (sz + 255) & ~(size_t)255;
    return r;
  };
  unsigned* flags = (unsigned*)alloc((size_t)3 * T_SZ * 64);  // 64B-strided counters
  __bf16* x1h = (__bf16*)alloc((size_t)B_SZ * T_SZ * NFILT * 2);
  __bf16* x1l = (__bf16*)alloc((size_t)B_SZ * T_SZ * NFILT * 2);
  __bf16* xAh = (__bf16*)alloc((size_t)B_SZ * T_SZ * H_SZ * 2);
  __bf16* xAl = (__bf16*)alloc((size_t)B_SZ * T_SZ * H_SZ * 2);
  __bf16* xBh = (__bf16*)alloc((size_t)B_SZ * T_SZ * H_SZ * 2);
  __bf16* xBl = (__bf16*)alloc((size_t)B_SZ * T_SZ * H_SZ * 2);
  __bf16* hbase = (__bf16*)alloc((size_t)2 * 3 * 2 * 16384 * 2);
  float* feat = (float*)alloc((size_t)B_SZ * H_SZ * 4);

  hipMemsetAsync(flags, 0, (size_t)3 * T_SZ * 64, stream);
  conv_gn_kernel<<<dim3(256), dim3(256), (64 * 520 + 16) * 4, stream>>>(
      x_emg, conv_w, gn_g, gn_b, x1h, x1l);
  lstm_scan_kernel<<<dim3(96), dim3(256), 0, stream>>>(
      wih1, whh1, b1, wih2, whh2, b2, wih3, whh3, b3,
      x1h, x1l, xAh, xAl, xBh, xBl, hbase, feat, flags);
  head_kernel<<<dim3(B_SZ * N_CLS), dim3(64), 0, stream>>>(feat, head_w, head_b, out);
}

// Round 3
// 4499.517 us; speedup vs baseline: 1.2614x; 1.0864x over previous
//
#include <hip/hip_runtime.h>
#include <stdint.h>
#include <math.h>

// ---------------- problem constants ----------------
#define B_SZ 32
#define C_IN 64
#define T_SZ 512
#define NFILT 256
#define KW 9
#define H_SZ 512
#define N_CLS 50

typedef __bf16 bf16x8 __attribute__((ext_vector_type(8)));
typedef float f32x16 __attribute__((ext_vector_type(16)));

#define MFMA32(a, b, c) __builtin_amdgcn_mfma_f32_32x32x16_bf16((a), (b), (c), 0, 0, 0)

// fast transcendentals: single HW instructions, no ocml calls (keeps VGPR live ranges intact)
__device__ __forceinline__ float fast_sigmoid(float x) {
  return __builtin_amdgcn_rcpf(1.f + __builtin_amdgcn_exp2f(-1.442695040889f * x));
}
__device__ __forceinline__ float fast_tanh(float x) {
  return 1.f - 2.f * __builtin_amdgcn_rcpf(1.f + __builtin_amdgcn_exp2f(2.885390081778f * x));
}

// system-scope (LLC-coherent, cache-bypassing) data movement for cross-XCD exchange
__device__ __forceinline__ bf16x8 ld_frag_sys(const __bf16* p) {
  union { unsigned long long u[2]; bf16x8 v; } r;
  r.u[0] = __hip_atomic_load((const unsigned long long*)p, __ATOMIC_RELAXED,
                             __HIP_MEMORY_SCOPE_SYSTEM);
  r.u[1] = __hip_atomic_load((const unsigned long long*)(p + 4), __ATOMIC_RELAXED,
                             __HIP_MEMORY_SCOPE_SYSTEM);
  return r.v;
}
__device__ __forceinline__ void st_u32_sys(unsigned* p, unsigned v) {
  __hip_atomic_store(p, v, __ATOMIC_RELAXED, __HIP_MEMORY_SCOPE_SYSTEM);
}
// per-producer progress words, 4B stride: one poll = one coalesced 32-lane load
__device__ __forceinline__ void wait_prog(const unsigned* prog, unsigned target) {
  const unsigned* p = prog + (threadIdx.x & 31);
  while (true) {
    unsigned v = __hip_atomic_load(p, __ATOMIC_RELAXED, __HIP_MEMORY_SCOPE_SYSTEM);
    if (__all((int)(v >= target))) break;
  }
}

// ---------------- conv1d + groupnorm + relu, write bf16 hi/lo (B,T,F) ----------------
__global__ __launch_bounds__(256, 1) void conv_gn_kernel(
    const float* __restrict__ x, const float* __restrict__ w,
    const float* __restrict__ gamma, const float* __restrict__ beta,
    __bf16* __restrict__ x1h, __bf16* __restrict__ x1l) {
  extern __shared__ float xs[];  // [64][520] padded rows + 16 floats reduction
  const int b = blockIdx.x >> 3;
  const int g = blockIdx.x & 7;
  const int tid = threadIdx.x;
  const float* xb = x + (size_t)b * (C_IN * T_SZ);
  for (int i = tid; i < C_IN * T_SZ / 4; i += 256) {
    int c = i >> 7;
    int t4 = (i & 127) << 2;
    float4 v = *(const float4*)(xb + c * T_SZ + t4);
    *(float4*)(&xs[c * 520 + 4 + t4]) = v;
  }
  for (int i = tid; i < C_IN * 8; i += 256) {
    int c = i >> 3, j = i & 7;
    xs[c * 520 + (j < 4 ? j : 512 + j)] = 0.f;
  }
  __syncthreads();
  const int fl = tid & 31;
  const int f = g * 32 + fl;
  const int t0 = (tid >> 5) << 6;
  float acc[64];
#pragma unroll
  for (int t = 0; t < 64; ++t) acc[t] = 0.f;
  const float* wf = w + (size_t)f * (C_IN * KW);
  for (int c = 0; c < C_IN; ++c) {
    float wr[9];
#pragma unroll
    for (int k = 0; k < 9; ++k) wr[k] = wf[c * 9 + k];
    float xr[72];
    const float* xrow = &xs[c * 520 + t0];
#pragma unroll
    for (int j = 0; j < 72; ++j) xr[j] = xrow[j];
#pragma unroll
    for (int t = 0; t < 64; ++t) {
      float s = acc[t];
#pragma unroll
      for (int k = 0; k < 9; ++k) s = fmaf(xr[t + k], wr[k], s);
      acc[t] = s;
    }
  }
  float s1 = 0.f, s2 = 0.f;
#pragma unroll
  for (int t = 0; t < 64; ++t) { s1 += acc[t]; s2 = fmaf(acc[t], acc[t], s2); }
#pragma unroll
  for (int off = 32; off > 0; off >>= 1) {
    s1 += __shfl_down(s1, off);
    s2 += __shfl_down(s2, off);
  }
  float* red = xs + 64 * 520;
  if ((tid & 63) == 0) { red[tid >> 6] = s1; red[4 + (tid >> 6)] = s2; }
  __syncthreads();
  if (tid == 0) {
    float a = red[0] + red[1] + red[2] + red[3];
    float q = red[4] + red[5] + red[6] + red[7];
    float mu = a * (1.f / 16384.f);
    float var = q * (1.f / 16384.f) - mu * mu;
    red[8] = mu;
    red[9] = 1.f / sqrtf(var + 1e-5f);
  }
  __syncthreads();
  const float mu = red[8], inv = red[9];
  const float ga = gamma[f], be = beta[f];
#pragma unroll
  for (int t = 0; t < 64; ++t) {
    float v = (acc[t] - mu) * inv * ga + be;
    v = fmaxf(v, 0.f);
    __bf16 hh = (__bf16)v;
    __bf16 hl = (__bf16)(v - (float)hh);
    size_t idx = ((size_t)b * T_SZ + (t0 + t)) * NFILT + f;
    x1h[idx] = hh;
    x1l[idx] = hl;
  }
}

// ---------------- self-timed pipelined 3-layer LSTM scan ----------------
// 96 WGs x 256 threads. WG = (layer = wg/32, wgl = wg%32 -> units [wgl*16, wgl*16+16)).
// Waves 0,1 = recurrent k-halves (poll prog[layer] >= t); waves 2,3 = xproj (poll
// prog[layer-1] >= t+1). prog[l][wg] = completed steps, plain sc0sc1 store (no atomics).
// h exchange via sc0sc1 LLC ops; x streams plain cached reads (first-touch), LLC writes.
// Weights resident in VGPRs, fp32-ish via bf16 hi/lo 3-pass MFMA.
__global__ __launch_bounds__(256, 1) void lstm_scan_kernel(
    const float* __restrict__ wih1, const float* __restrict__ whh1, const float* __restrict__ bb1,
    const float* __restrict__ wih2, const float* __restrict__ whh2, const float* __restrict__ bb2,
    const float* __restrict__ wih3, const float* __restrict__ whh3, const float* __restrict__ bb3,
    const __bf16* __restrict__ x1h, const __bf16* __restrict__ x1l,
    __bf16* __restrict__ xAh, __bf16* __restrict__ xAl,
    __bf16* __restrict__ xBh, __bf16* __restrict__ xBl,
    __bf16* __restrict__ hbase,  // [parity2][layer3][hi/lo2][32*512]
    float* __restrict__ feat, unsigned* __restrict__ prog) {
  __shared__ float gl[4][32][72];  // per-wave partial gate tiles, stride 72

  const int wg = blockIdx.x;
  const int layer = wg >> 5;
  const int wgl = wg & 31;
  const int tid = threadIdx.x;
  const int lane = tid & 63;
  const int wave = tid >> 6;

  const float* wih = layer == 0 ? wih1 : (layer == 1 ? wih2 : wih3);
  const float* whh = layer == 0 ? whh1 : (layer == 1 ? whh2 : whh3);
  const float* bias = layer == 0 ? bb1 : (layer == 1 ? bb2 : bb3);
  const int Din = layer == 0 ? NFILT : H_SZ;
  const __bf16* xinh = layer == 0 ? x1h : (layer == 1 ? xAh : xBh);
  const __bf16* xinl = layer == 0 ? x1l : (layer == 1 ? xAl : xBl);
  __bf16* xoh = layer == 0 ? xAh : xBh;
  __bf16* xol = layer == 0 ? xAl : xBl;
  unsigned* prog_self = prog + layer * 32;
  const unsigned* prog_up = prog + (layer - 1) * 32;

  const bool is_x = (wave >= 2);
  const int kbase = (wave & 1) << 8;
  const bool dead = (layer == 0) && (wave == 3);  // layer0 x-k [256,512) doesn't exist

  // ---- resident weight fragments (hi/lo bf16 split) ----
  bf16x8 wfh[2][16], wfl[2][16];
  {
    const float* wsrc = is_x ? wih : whh;
    const int wk = is_x ? Din : H_SZ;
#pragma unroll
    for (int nt = 0; nt < 2; ++nt) {
      const int nloc = nt * 32 + (lane & 31);
      const int orow = (nloc >> 4) * 512 + wgl * 16 + (nloc & 15);
      const float* wrow = wsrc + (size_t)orow * wk;
#pragma unroll
      for (int kt = 0; kt < 16; ++kt) {
        const int k0 = kbase + kt * 16 + ((lane >> 5) << 3);
        bf16x8 hi, lo;
#pragma unroll
        for (int e = 0; e < 8; ++e) {
          float v = 0.f;
          if (!is_x || (k0 + e) < Din) v = wrow[k0 + e];
          __bf16 h = (__bf16)v;
          hi[e] = h;
          lo[e] = (__bf16)(v - (float)h);
        }
        wfh[nt][kt] = hi;
        wfl[nt][kt] = lo;
      }
    }
  }

  // ---- cell-update mapping: thread -> batch row cm, unit pair ----
  const int cm = tid >> 3;
  const int cq = tid & 7;
  const int ul0 = cq * 2;
  const int unit0 = wgl * 16 + ul0;
  float cb[4][2];
#pragma unroll
  for (int gg = 0; gg < 4; ++gg) {
    cb[gg][0] = bias[gg * 512 + unit0];
    cb[gg][1] = bias[gg * 512 + unit0 + 1];
  }
  float cst[2] = {0.f, 0.f};
  float hsum[2] = {0.f, 0.f};

  const int arow = lane & 31;         // A row = batch
  const int agrp = (lane >> 5) << 3;  // k sub-group 0/8

  for (int t = 0; t < T_SZ; ++t) {
    f32x16 acc[2][2] = {};  // [ntile][kt parity]
    if (!is_x) {
      if (t > 0) {  // h_{-1} = 0 -> skip recurrent MFMAs at t==0
        wait_prog(prog_self, (unsigned)t);
        const int rp = (t - 1) & 1;
        const __bf16* hb = hbase + ((size_t)(rp * 3 + layer) * 2) * 16384;
        const __bf16* ahb = hb + (size_t)arow * 512;
        const __bf16* alb = hb + 16384 + (size_t)arow * 512;
#pragma unroll
        for (int kt = 0; kt < 16; ++kt) {
          const int k0 = kbase + kt * 16 + agrp;
          const bf16x8 ah = ld_frag_sys(ahb + k0);
          const bf16x8 al = ld_frag_sys(alb + k0);
          const int p = kt & 1;
#pragma unroll
          for (int nt = 0; nt < 2; ++nt) {
            f32x16 a = acc[nt][p];
            a = MFMA32(ah, wfh[nt][kt], a);
            a = MFMA32(al, wfh[nt][kt], a);
            a = MFMA32(ah, wfl[nt][kt], a);
            acc[nt][p] = a;
          }
        }
      }
    } else if (!dead) {
      if (layer > 0) wait_prog(prog_up, (unsigned)(t + 1));
      const __bf16* ahb = xinh + ((size_t)arow * T_SZ + t) * Din;
      const __bf16* alb = xinl + ((size_t)arow * T_SZ + t) * Din;
#pragma unroll
      for (int kt = 0; kt < 16; ++kt) {
        const int k0 = kbase + kt * 16 + agrp;
        const bf16x8 ah = *(const bf16x8*)(ahb + k0);
        const bf16x8 al = *(const bf16x8*)(alb + k0);
        const int p = kt & 1;
#pragma unroll
        for (int nt = 0; nt < 2; ++nt) {
          f32x16 a = acc[nt][p];
          a = MFMA32(ah, wfh[nt][kt], a);
          a = MFMA32(al, wfh[nt][kt], a);
          a = MFMA32(ah, wfl[nt][kt], a);
          acc[nt][p] = a;
        }
      }
    }
    // publish partial gate tiles
#pragma unroll
    for (int nt = 0; nt < 2; ++nt) {
      const f32x16 v = acc[nt][0] + acc[nt][1];
      const int n = nt * 32 + (lane & 31);
#pragma unroll
      for (int r = 0; r < 16; ++r) {
        const int m = (r & 3) + ((r >> 2) << 3) + ((lane >> 5) << 2);
        gl[wave][m][n] = v[r];
      }
    }
    __syncthreads();
    // cell update: 2 consecutive units at batch row cm
    {
      __bf16* hw = hbase + ((size_t)((t & 1) * 3 + layer) * 2) * 16384;
      float hv[2];
#pragma unroll
      for (int j = 0; j < 2; ++j) {
        float gv[4];
#pragma unroll
        for (int gg = 0; gg < 4; ++gg) {
          gv[gg] = gl[0][cm][gg * 16 + ul0 + j] + gl[1][cm][gg * 16 + ul0 + j] +
                   gl[2][cm][gg * 16 + ul0 + j] + gl[3][cm][gg * 16 + ul0 + j] + cb[gg][j];
        }
        const float ig = fast_sigmoid(gv[0]);
        const float fg = fast_sigmoid(gv[1]);
        const float gc = fast_tanh(gv[2]);
        const float og = fast_sigmoid(gv[3]);
        const float c_ = fg * cst[j] + ig * gc;
        cst[j] = c_;
        hv[j] = og * fast_tanh(c_);
      }
      union { __bf16 b[2]; unsigned u; } ph, pl;
      ph.b[0] = (__bf16)hv[0];
      ph.b[1] = (__bf16)hv[1];
      pl.b[0] = (__bf16)(hv[0] - (float)ph.b[0]);
      pl.b[1] = (__bf16)(hv[1] - (float)ph.b[1]);
      st_u32_sys((unsigned*)(hw + (size_t)cm * 512 + unit0), ph.u);
      st_u32_sys((unsigned*)(hw + 16384 + (size_t)cm * 512 + unit0), pl.u);
      if (layer < 2) {
        const size_t xo = ((size_t)cm * T_SZ + t) * 512 + unit0;
        st_u32_sys((unsigned*)(xoh + xo), ph.u);
        st_u32_sys((unsigned*)(xol + xo), pl.u);
      } else {
        hsum[0] += hv[0];
        hsum[1] += hv[1];
      }
    }
    __syncthreads();  // drains vmem (stores ack'd at LLC) + closes gl read phase
    if (tid == 0) st_u32_sys(prog_self + wgl, (unsigned)(t + 1));
  }
  if (layer == 2) {
    feat[(size_t)cm * 512 + unit0] = hsum[0] * (1.f / 512.f);
    feat[(size_t)cm * 512 + unit0 + 1] = hsum[1] * (1.f / 512.f);
  }
}

// ---------------- head ----------------
__global__ void head_kernel(const float* __restrict__ feat, const float* __restrict__ hw,
                            const float* __restrict__ hb, float* __restrict__ out) {
  const int bi = blockIdx.x;
  const int b = bi / N_CLS;
  const int n = bi % N_CLS;
  const int lane = threadIdx.x;
  float s = 0.f;
  for (int j = lane; j < H_SZ; j += 64) s = fmaf(feat[b * H_SZ + j], hw[n * H_SZ + j], s);
#pragma unroll
  for (int off = 32; off > 0; off >>= 1) s += __shfl_down(s, off);
  if (lane == 0) out[b * N_CLS + n] = s + hb[n];
}

// ---------------- launch ----------------
extern "C" void kernel_launch(void* const* d_in, const int* in_sizes, int n_in,
                              void* d_out, int out_size, void* d_ws, size_t ws_size,
                              hipStream_t stream) {
  const float* x_emg = (const float*)d_in[0];
  const float* conv_w = (const float*)d_in[1];
  const float* gn_g = (const float*)d_in[2];
  const float* gn_b = (const float*)d_in[3];
  const float* head_w = (const float*)d_in[4];
  const float* head_b = (const float*)d_in[5];
  const float* wih1 = (const float*)d_in[6];
  const float* whh1 = (const float*)d_in[7];
  const float* b1 = (const float*)d_in[8];
  const float* wih2 = (const float*)d_in[9];
  const float* whh2 = (const float*)d_in[10];
  const float* b2 = (const float*)d_in[11];
  const float* wih3 = (const float*)d_in[12];
  const float* whh3 = (const float*)d_in[13];
  const float* b3 = (const float*)d_in[14];
  float* out = (float*)d_out;

  char* p = (char*)d_ws;
  auto alloc = [&](size_t sz) {
    char* r = p;
    p += (sz + 255) & ~(size_t)255;
    return r;
  };
  unsigned* prog = (unsigned*)alloc(512);  // 3*32 progress words, 4B stride
  __bf16* x1h = (__bf16*)alloc((size_t)B_SZ * T_SZ * NFILT * 2);
  __bf16* x1l = (__bf16*)alloc((size_t)B_SZ * T_SZ * NFILT * 2);
  __bf16* xAh = (__bf16*)alloc((size_t)B_SZ * T_SZ * H_SZ * 2);
  __bf16* xAl = (__bf16*)alloc((size_t)B_SZ * T_SZ * H_SZ * 2);
  __bf16* xBh = (__bf16*)alloc((size_t)B_SZ * T_SZ * H_SZ * 2);
  __bf16* xBl = (__bf16*)alloc((size_t)B_SZ * T_SZ * H_SZ * 2);
  __bf16* hbase = (__bf16*)alloc((size_t)2 * 3 * 2 * 16384 * 2);
  float* feat = (float*)alloc((size_t)B_SZ * H_SZ * 4);

  hipMemsetAsync(prog, 0, 512, stream);
  conv_gn_kernel<<<dim3(256), dim3(256), (64 * 520 + 16) * 4, stream>>>(
      x_emg, conv_w, gn_g, gn_b, x1h, x1l);
  lstm_scan_kernel<<<dim3(96), dim3(256), 0, stream>>>(
      wih1, whh1, b1, wih2, whh2, b2, wih3, whh3, b3,
      x1h, x1l, xAh, xAl, xBh, xBl, hbase, feat, prog);
  head_kernel<<<dim3(B_SZ * N_CLS), dim3(64), 0, stream>>>(feat, head_w, head_b, out);
}

// Round 4
// 3938.788 us; speedup vs baseline: 1.4409x; 1.1424x over previous
//
#include <hip/hip_runtime.h>
#include <stdint.h>
#include <math.h>

// ---------------- problem constants ----------------
#define B_SZ 32
#define C_IN 64
#define T_SZ 512
#define NFILT 256
#define KW 9
#define H_SZ 512
#define N_CLS 50

typedef __bf16 bf16x8 __attribute__((ext_vector_type(8)));
typedef float f32x16 __attribute__((ext_vector_type(16)));

#define MFMA32(a, b, c) __builtin_amdgcn_mfma_f32_32x32x16_bf16((a), (b), (c), 0, 0, 0)

// fast transcendentals: single HW instructions, no ocml calls
__device__ __forceinline__ float fast_sigmoid(float x) {
  return __builtin_amdgcn_rcpf(1.f + __builtin_amdgcn_exp2f(-1.442695040889f * x));
}
__device__ __forceinline__ float fast_tanh(float x) {
  return 1.f - 2.f * __builtin_amdgcn_rcpf(1.f + __builtin_amdgcn_exp2f(2.885390081778f * x));
}

// system-scope (LLC-coherent, cache-bypassing) ops for cross-XCD h exchange.
// With fragment layout, lane addresses are 16B-stride -> coalesced (8 line-txn/instr).
__device__ __forceinline__ bf16x8 ld_frag_sys(const __bf16* p) {
  union { unsigned long long u[2]; bf16x8 v; } r;
  r.u[0] = __hip_atomic_load((const unsigned long long*)p, __ATOMIC_RELAXED,
                             __HIP_MEMORY_SCOPE_SYSTEM);
  r.u[1] = __hip_atomic_load((const unsigned long long*)(p + 4), __ATOMIC_RELAXED,
                             __HIP_MEMORY_SCOPE_SYSTEM);
  return r.v;
}
__device__ __forceinline__ void st_u32_sys(unsigned* p, unsigned v) {
  __hip_atomic_store(p, v, __ATOMIC_RELAXED, __HIP_MEMORY_SCOPE_SYSTEM);
}
// per-producer progress words, 4B stride: one poll = one coalesced 32-lane load
__device__ __forceinline__ void wait_prog(const unsigned* prog, unsigned target) {
  const unsigned* p = prog + (threadIdx.x & 31);
  while (true) {
    unsigned v = __hip_atomic_load(p, __ATOMIC_RELAXED, __HIP_MEMORY_SCOPE_SYSTEM);
    if (__all((int)(v >= target))) break;
  }
}

// A-fragment layout for a 32(batch) x K matrix, 16-k tiles:
//   ktg = k>>4, lane = row + 32*((k&15)>>3), elem = k&7
//   elem offset = (ktg*64 + lane)*8 + elem     (per plane; hi/lo planes separate)
// Consumer lane l of fragment ktg reads elems [(ktg*64+l)*8, +8) -> 16B coalesced.

// ---------------- conv1d + groupnorm + relu -> x1 fragments (per t) ----------------
__global__ __launch_bounds__(256, 1) void conv_gn_kernel(
    const float* __restrict__ x, const float* __restrict__ w,
    const float* __restrict__ gamma, const float* __restrict__ beta,
    __bf16* __restrict__ x1h, __bf16* __restrict__ x1l) {
  extern __shared__ float xs[];  // [64][520] padded rows + 16 floats reduction
  const int b = blockIdx.x >> 3;
  const int g = blockIdx.x & 7;
  const int tid = threadIdx.x;
  const float* xb = x + (size_t)b * (C_IN * T_SZ);
  for (int i = tid; i < C_IN * T_SZ / 4; i += 256) {
    int c = i >> 7;
    int t4 = (i & 127) << 2;
    float4 v = *(const float4*)(xb + c * T_SZ + t4);
    *(float4*)(&xs[c * 520 + 4 + t4]) = v;
  }
  for (int i = tid; i < C_IN * 8; i += 256) {
    int c = i >> 3, j = i & 7;
    xs[c * 520 + (j < 4 ? j : 512 + j)] = 0.f;
  }
  __syncthreads();
  const int fl = tid & 31;
  const int f = g * 32 + fl;
  const int t0 = (tid >> 5) << 6;
  float acc[64];
#pragma unroll
  for (int t = 0; t < 64; ++t) acc[t] = 0.f;
  const float* wf = w + (size_t)f * (C_IN * KW);
  for (int c = 0; c < C_IN; ++c) {
    float wr[9];
#pragma unroll
    for (int k = 0; k < 9; ++k) wr[k] = wf[c * 9 + k];
    float xr[72];
    const float* xrow = &xs[c * 520 + t0];
#pragma unroll
    for (int j = 0; j < 72; ++j) xr[j] = xrow[j];
#pragma unroll
    for (int t = 0; t < 64; ++t) {
      float s = acc[t];
#pragma unroll
      for (int k = 0; k < 9; ++k) s = fmaf(xr[t + k], wr[k], s);
      acc[t] = s;
    }
  }
  float s1 = 0.f, s2 = 0.f;
#pragma unroll
  for (int t = 0; t < 64; ++t) { s1 += acc[t]; s2 = fmaf(acc[t], acc[t], s2); }
#pragma unroll
  for (int off = 32; off > 0; off >>= 1) {
    s1 += __shfl_down(s1, off);
    s2 += __shfl_down(s2, off);
  }
  float* red = xs + 64 * 520;
  if ((tid & 63) == 0) { red[tid >> 6] = s1; red[4 + (tid >> 6)] = s2; }
  __syncthreads();
  if (tid == 0) {
    float a = red[0] + red[1] + red[2] + red[3];
    float q = red[4] + red[5] + red[6] + red[7];
    float mu = a * (1.f / 16384.f);
    float var = q * (1.f / 16384.f) - mu * mu;
    red[8] = mu;
    red[9] = 1.f / sqrtf(var + 1e-5f);
  }
  __syncthreads();
  const float mu = red[8], inv = red[9];
  const float ga = gamma[f], be = beta[f];
  // fragment coords for filter f (Din=256 -> per-t plane = 8192 elems)
  const int ktg = f >> 4;
  const int lane32 = b + 32 * ((f >> 3) & 1);
  const int elem = f & 7;  // even/odd pairs merged via shfl
  const size_t fo = (size_t)(ktg * 64 + lane32) * 8 + (elem & ~1);
#pragma unroll
  for (int t = 0; t < 64; ++t) {
    float v = (acc[t] - mu) * inv * ga + be;
    v = fmaxf(v, 0.f);
    __bf16 hh = (__bf16)v;
    __bf16 hl = (__bf16)(v - (float)hh);
    unsigned hu = (unsigned)__builtin_bit_cast(unsigned short, hh);
    unsigned lu = (unsigned)__builtin_bit_cast(unsigned short, hl);
    unsigned hu_p = __shfl_xor(hu, 1);
    unsigned lu_p = __shfl_xor(lu, 1);
    if ((fl & 1) == 0) {
      const size_t off = (size_t)(t0 + t) * 8192 + fo;
      *(unsigned*)(x1h + off) = hu | (hu_p << 16);
      *(unsigned*)(x1l + off) = lu | (lu_p << 16);
    }
  }
}

// ---------------- self-timed pipelined 3-layer LSTM scan (fragment-layout exchange) ----
// 96 WGs x 256 threads. WG = (layer = wg/32, wgl = wg%32 -> units [wgl*16, wgl*16+16)).
// Waves 0,1 = recurrent k-halves (poll prog[layer] >= t); waves 2,3 = xproj (poll
// prog[layer-1] >= t+1). h exchange sc0sc1 (LLC) in A-fragment layout (coalesced);
// x streams plain cached reads of fragment buffers. Weights resident, hi/lo 3-pass MFMA.
__global__ __launch_bounds__(256, 1) void lstm_scan_kernel(
    const float* __restrict__ wih1, const float* __restrict__ whh1, const float* __restrict__ bb1,
    const float* __restrict__ wih2, const float* __restrict__ whh2, const float* __restrict__ bb2,
    const float* __restrict__ wih3, const float* __restrict__ whh3, const float* __restrict__ bb3,
    const __bf16* __restrict__ x1h, const __bf16* __restrict__ x1l,
    __bf16* __restrict__ xAh, __bf16* __restrict__ xAl,
    __bf16* __restrict__ xBh, __bf16* __restrict__ xBl,
    __bf16* __restrict__ hbase,  // [parity2][layer3][hi/lo2][16384 elems] fragments
    float* __restrict__ feat, unsigned* __restrict__ prog) {
  __shared__ float gl[4][32][72];

  const int wg = blockIdx.x;
  const int layer = wg >> 5;
  const int wgl = wg & 31;
  const int tid = threadIdx.x;
  const int lane = tid & 63;
  const int wave = tid >> 6;

  const float* wih = layer == 0 ? wih1 : (layer == 1 ? wih2 : wih3);
  const float* whh = layer == 0 ? whh1 : (layer == 1 ? whh2 : whh3);
  const float* bias = layer == 0 ? bb1 : (layer == 1 ? bb2 : bb3);
  const int Din = layer == 0 ? NFILT : H_SZ;
  const __bf16* xinh = layer == 0 ? x1h : (layer == 1 ? xAh : xBh);
  const __bf16* xinl = layer == 0 ? x1l : (layer == 1 ? xAl : xBl);
  __bf16* xoh = layer == 0 ? xAh : xBh;
  __bf16* xol = layer == 0 ? xAl : xBl;
  const size_t xin_tstride = (layer == 0) ? 8192 : 16384;  // elems per t per plane
  unsigned* prog_self = prog + layer * 32;
  const unsigned* prog_up = prog + (layer - 1) * 32;

  const bool is_x = (wave >= 2);
  const int kbase = (wave & 1) << 8;
  const bool dead = (layer == 0) && (wave == 3);

  // ---- resident weight fragments (hi/lo bf16 split) ----
  bf16x8 wfh[2][16], wfl[2][16];
  {
    const float* wsrc = is_x ? wih : whh;
    const int wk = is_x ? Din : H_SZ;
#pragma unroll
    for (int nt = 0; nt < 2; ++nt) {
      const int nloc = nt * 32 + (lane & 31);
      const int orow = (nloc >> 4) * 512 + wgl * 16 + (nloc & 15);
      const float* wrow = wsrc + (size_t)orow * wk;
#pragma unroll
      for (int kt = 0; kt < 16; ++kt) {
        const int k0 = kbase + kt * 16 + ((lane >> 5) << 3);
        bf16x8 hi, lo;
#pragma unroll
        for (int e = 0; e < 8; ++e) {
          float v = 0.f;
          if (!is_x || (k0 + e) < Din) v = wrow[k0 + e];
          __bf16 h = (__bf16)v;
          hi[e] = h;
          lo[e] = (__bf16)(v - (float)h);
        }
        wfh[nt][kt] = hi;
        wfl[nt][kt] = lo;
      }
    }
  }

  // ---- cell-update mapping: thread -> batch row cm, unit pair ----
  const int cm = tid >> 3;
  const int cq = tid & 7;
  const int ul0 = cq * 2;
  const int unit0 = wgl * 16 + ul0;
  float cb[4][2];
#pragma unroll
  for (int gg = 0; gg < 4; ++gg) {
    cb[gg][0] = bias[gg * 512 + unit0];
    cb[gg][1] = bias[gg * 512 + unit0 + 1];
  }
  float cst[2] = {0.f, 0.f};
  float hsum[2] = {0.f, 0.f};

  // producer fragment offset (within a 16384-elem plane): units unit0,unit0+1 at row cm
  const size_t pf = (size_t)(wgl * 64 + cm + 32 * (ul0 >> 3)) * 8 + (ul0 & 7);
  // consumer fragment base ktg for this wave's k-half
  const int ktg0 = kbase >> 4;

  for (int t = 0; t < T_SZ; ++t) {
    f32x16 acc[2][2] = {};
    if (!is_x) {
      if (t > 0) {
        wait_prog(prog_self, (unsigned)t);
        const int rp = (t - 1) & 1;
        const __bf16* hbh = hbase + ((size_t)((rp * 3 + layer) * 2)) * 16384;
        const __bf16* hbl = hbh + 16384;
#pragma unroll
        for (int kt = 0; kt < 16; ++kt) {
          const size_t fo = (size_t)((ktg0 + kt) * 64 + lane) * 8;
          const bf16x8 ah = ld_frag_sys(hbh + fo);
          const bf16x8 al = ld_frag_sys(hbl + fo);
          const int p = kt & 1;
#pragma unroll
          for (int nt = 0; nt < 2; ++nt) {
            f32x16 a = acc[nt][p];
            a = MFMA32(ah, wfh[nt][kt], a);
            a = MFMA32(al, wfh[nt][kt], a);
            a = MFMA32(ah, wfl[nt][kt], a);
            acc[nt][p] = a;
          }
        }
      }
    } else if (!dead) {
      if (layer > 0) wait_prog(prog_up, (unsigned)(t + 1));
      const __bf16* xbh = xinh + (size_t)t * xin_tstride;
      const __bf16* xbl = xinl + (size_t)t * xin_tstride;
#pragma unroll
      for (int kt = 0; kt < 16; ++kt) {
        const size_t fo = (size_t)((ktg0 + kt) * 64 + lane) * 8;
        const bf16x8 ah = *(const bf16x8*)(xbh + fo);
        const bf16x8 al = *(const bf16x8*)(xbl + fo);
        const int p = kt & 1;
#pragma unroll
        for (int nt = 0; nt < 2; ++nt) {
          f32x16 a = acc[nt][p];
          a = MFMA32(ah, wfh[nt][kt], a);
          a = MFMA32(al, wfh[nt][kt], a);
          a = MFMA32(ah, wfl[nt][kt], a);
          acc[nt][p] = a;
        }
      }
    }
    // publish partial gate tiles
#pragma unroll
    for (int nt = 0; nt < 2; ++nt) {
      const f32x16 v = acc[nt][0] + acc[nt][1];
      const int n = nt * 32 + (lane & 31);
#pragma unroll
      for (int r = 0; r < 16; ++r) {
        const int m = (r & 3) + ((r >> 2) << 3) + ((lane >> 5) << 2);
        gl[wave][m][n] = v[r];
      }
    }
    __syncthreads();
    // cell update: 2 consecutive units at batch row cm
    {
      __bf16* hwh = hbase + ((size_t)(((t & 1) * 3 + layer) * 2)) * 16384;
      __bf16* hwl = hwh + 16384;
      float hv[2];
#pragma unroll
      for (int j = 0; j < 2; ++j) {
        float gv[4];
#pragma unroll
        for (int gg = 0; gg < 4; ++gg) {
          gv[gg] = gl[0][cm][gg * 16 + ul0 + j] + gl[1][cm][gg * 16 + ul0 + j] +
                   gl[2][cm][gg * 16 + ul0 + j] + gl[3][cm][gg * 16 + ul0 + j] + cb[gg][j];
        }
        const float ig = fast_sigmoid(gv[0]);
        const float fg = fast_sigmoid(gv[1]);
        const float gc = fast_tanh(gv[2]);
        const float og = fast_sigmoid(gv[3]);
        const float c_ = fg * cst[j] + ig * gc;
        cst[j] = c_;
        hv[j] = og * fast_tanh(c_);
      }
      union { __bf16 b[2]; unsigned u; } ph, pl;
      ph.b[0] = (__bf16)hv[0];
      ph.b[1] = (__bf16)hv[1];
      pl.b[0] = (__bf16)(hv[0] - (float)ph.b[0]);
      pl.b[1] = (__bf16)(hv[1] - (float)ph.b[1]);
      st_u32_sys((unsigned*)(hwh + pf), ph.u);
      st_u32_sys((unsigned*)(hwl + pf), pl.u);
      if (layer < 2) {
        const size_t xo = (size_t)t * 16384 + pf;
        st_u32_sys((unsigned*)(xoh + xo), ph.u);
        st_u32_sys((unsigned*)(xol + xo), pl.u);
      } else {
        hsum[0] += hv[0];
        hsum[1] += hv[1];
      }
    }
    __syncthreads();  // all waves' stores drained (vmcnt0 before barrier)
    if (tid == 0) st_u32_sys(prog_self + wgl, (unsigned)(t + 1));
  }
  if (layer == 2) {
    feat[(size_t)cm * 512 + unit0] = hsum[0] * (1.f / 512.f);
    feat[(size_t)cm * 512 + unit0 + 1] = hsum[1] * (1.f / 512.f);
  }
}

// ---------------- head ----------------
__global__ void head_kernel(const float* __restrict__ feat, const float* __restrict__ hw,
                            const float* __restrict__ hb, float* __restrict__ out) {
  const int bi = blockIdx.x;
  const int b = bi / N_CLS;
  const int n = bi % N_CLS;
  const int lane = threadIdx.x;
  float s = 0.f;
  for (int j = lane; j < H_SZ; j += 64) s = fmaf(feat[b * H_SZ + j], hw[n * H_SZ + j], s);
#pragma unroll
  for (int off = 32; off > 0; off >>= 1) s += __shfl_down(s, off);
  if (lane == 0) out[b * N_CLS + n] = s + hb[n];
}

// ---------------- launch ----------------
extern "C" void kernel_launch(void* const* d_in, const int* in_sizes, int n_in,
                              void* d_out, int out_size, void* d_ws, size_t ws_size,
                              hipStream_t stream) {
  const float* x_emg = (const float*)d_in[0];
  const float* conv_w = (const float*)d_in[1];
  const float* gn_g = (const float*)d_in[2];
  const float* gn_b = (const float*)d_in[3];
  const float* head_w = (const float*)d_in[4];
  const float* head_b = (const float*)d_in[5];
  const float* wih1 = (const float*)d_in[6];
  const float* whh1 = (const float*)d_in[7];
  const float* b1 = (const float*)d_in[8];
  const float* wih2 = (const float*)d_in[9];
  const float* whh2 = (const float*)d_in[10];
  const float* b2 = (const float*)d_in[11];
  const float* wih3 = (const float*)d_in[12];
  const float* whh3 = (const float*)d_in[13];
  const float* b3 = (const float*)d_in[14];
  float* out = (float*)d_out;

  char* p = (char*)d_ws;
  auto alloc = [&](size_t sz) {
    char* r = p;
    p += (sz + 255) & ~(size_t)255;
    return r;
  };
  unsigned* prog = (unsigned*)alloc(512);  // 3*32 progress words, 4B stride
  __bf16* x1h = (__bf16*)alloc((size_t)T_SZ * 8192 * 2);
  __bf16* x1l = (__bf16*)alloc((size_t)T_SZ * 8192 * 2);
  __bf16* xAh = (__bf16*)alloc((size_t)T_SZ * 16384 * 2);
  __bf16* xAl = (__bf16*)alloc((size_t)T_SZ * 16384 * 2);
  __bf16* xBh = (__bf16*)alloc((size_t)T_SZ * 16384 * 2);
  __bf16* xBl = (__bf16*)alloc((size_t)T_SZ * 16384 * 2);
  __bf16* hbase = (__bf16*)alloc((size_t)2 * 3 * 2 * 16384 * 2);
  float* feat = (float*)alloc((size_t)B_SZ * H_SZ * 4);

  hipMemsetAsync(prog, 0, 512, stream);
  conv_gn_kernel<<<dim3(256), dim3(256), (64 * 520 + 16) * 4, stream>>>(
      x_emg, conv_w, gn_g, gn_b, x1h, x1l);
  lstm_scan_kernel<<<dim3(96), dim3(256), 0, stream>>>(
      wih1, whh1, b1, wih2, whh2, b2, wih3, whh3, b3,
      x1h, x1l, xAh, xAl, xBh, xBl, hbase, feat, prog);
  head_kernel<<<dim3(B_SZ * N_CLS), dim3(64), 0, stream>>>(feat, head_w, head_b, out);
}